// Round 8
// baseline (282.074 us; speedup 1.0000x reference)
//
#include <hip/hip_runtime.h>

// Problem constants: B=32, L=2, F=65536, D=768
#define BB 32
#define LL 2
#define FF 65536
#define DD 768
#define F4 (FF / 4)        // 16384 groups of 4 f
#define LD (LL * DD)       // 1536
#define LD2 (LD / 2)       // 768 float2
#define D2 (DD / 2)        // 384 float2 per weight row

#define FT_FLOAT4S ((size_t)F4 * BB)            // 524288 float4 = 8.39 MB
#define FT_BYTES   (FT_FLOAT4S * sizeof(float4))
#define CHUNK_BYTES ((size_t)BB * LD * sizeof(float))  // 196608 B
#define SUBC 64                                  // groups staged per LDS round

#define FMA2(A, W, S)                                                          \
    do {                                                                       \
        (A).x = fmaf((W).x, (S), (A).x);                                       \
        (A).y = fmaf((W).y, (S), (A).y);                                       \
    } while (0)

// Stage 0: transpose f (B x F) -> fT[g][b] as float4.
__global__ __launch_bounds__(256) void cc_transpose(
    const float4* __restrict__ f4, float4* __restrict__ fT4)
{
    size_t t = (size_t)blockIdx.x * 256 + threadIdx.x;   // 0 .. F4*32-1
    if (t >= FT_FLOAT4S) return;
    int b = (int)(t / F4);
    int g = (int)(t - (size_t)b * F4);
    fT4[(size_t)g * BB + b] = f4[t];
}

// Stage 1: partial GEMM over an F-chunk. 4 waves/block, f staged in LDS.
// grid = (3, NF); block = 256.  wave w covers ct = bx*4 + w; l = ct/6, dt = ct%6.
// Each wave: d-tile of 128 (float2/lane), acc[32] float2 = 64 VGPR.
// partials[c][b][l*768 + dt*128 + lane*2]
__global__ __launch_bounds__(256, 4) void cc_stage1(
    const float4* __restrict__ fT4,     // [F4][32] float4
    const float* __restrict__ weight,   // L x F x D
    float* __restrict__ partials,       // NF x B x LD
    int chunk4)
{
    __shared__ float4 sf[SUBC * BB];    // 32 KB: f values for 64 groups

    const int tid  = threadIdx.x;
    const int lane = tid & 63;
    const int w    = tid >> 6;          // wave 0..3
    const int ct   = blockIdx.x * 4 + w;   // 0..11
    const int c    = blockIdx.y;           // chunk
    const int l    = ct / 6;
    const int dt   = ct - l * 6;

    const float2* __restrict__ w2p =
        (const float2*)weight + (size_t)l * FF * D2 + (size_t)dt * 64 + lane;

    int g0 = c * chunk4;
    int g1 = g0 + chunk4;
    if (g1 > F4) g1 = F4;

    float2 acc[BB];
#pragma unroll
    for (int b = 0; b < BB; ++b) acc[b] = make_float2(0.f, 0.f);

    // depth-1 weight prefetch for group g0
    float2 w0 = w2p[((size_t)g0 * 4 + 0) * D2];
    float2 w1 = w2p[((size_t)g0 * 4 + 1) * D2];
    float2 w2 = w2p[((size_t)g0 * 4 + 2) * D2];
    float2 w3 = w2p[((size_t)g0 * 4 + 3) * D2];

    for (int gs = g0; gs < g1; gs += SUBC) {
        int gcnt = g1 - gs;
        if (gcnt > SUBC) gcnt = SUBC;

        __syncthreads();   // previous round's LDS reads complete
        // cooperative stage: gcnt*32 float4s, fully coalesced
        for (int t = tid; t < gcnt * BB; t += 256)
            sf[t] = fT4[(size_t)gs * BB + t];
        __syncthreads();

        for (int gi = 0; gi < gcnt; ++gi) {
            const int g  = gs + gi;
            int gn = g + 1;
            if (gn >= g1) gn = g1 - 1;   // clamp: last iter reloads, harmless
            float2 n0 = w2p[((size_t)gn * 4 + 0) * D2];
            float2 n1 = w2p[((size_t)gn * 4 + 1) * D2];
            float2 n2 = w2p[((size_t)gn * 4 + 2) * D2];
            float2 n3 = w2p[((size_t)gn * 4 + 3) * D2];

            const float4* __restrict__ fr = sf + gi * BB;  // wave-uniform -> broadcast
#pragma unroll
            for (int b = 0; b < BB; ++b) {
                float4 fv = fr[b];
                FMA2(acc[b], w0, fv.x);
                FMA2(acc[b], w1, fv.y);
                FMA2(acc[b], w2, fv.z);
                FMA2(acc[b], w3, fv.w);
            }
            w0 = n0; w1 = n1; w2 = n2; w3 = n3;
        }
    }

    float2* __restrict__ out2 =
        (float2*)partials + (size_t)c * BB * LD2 + (size_t)(l * 384 + dt * 64 + lane);
#pragma unroll
    for (int b = 0; b < BB; ++b)
        out2[(size_t)b * LD2] = acc[b];
}

// Stage 2: out[b, ld] = bias[ld] + sum_c partials[c][b][ld]
__global__ __launch_bounds__(256) void cc_stage2(
    const float* __restrict__ partials,
    const float* __restrict__ bias,
    float* __restrict__ out,
    int nf)
{
    int o = blockIdx.x * 256 + threadIdx.x;   // 0 .. B*LD-1
    if (o >= BB * LD) return;
    int b  = o / LD;
    int ld = o - b * LD;
    float s = bias[ld];
    const float* __restrict__ p = partials + (size_t)b * LD + ld;
#pragma unroll 16
    for (int c = 0; c < nf; ++c)
        s += p[(size_t)c * (BB * LD)];
    out[o] = s;
}

// Correctness-only fallback if workspace is too small.
__global__ __launch_bounds__(256) void cc_direct(
    const float* __restrict__ f,
    const float* __restrict__ weight,
    const float* __restrict__ bias,
    float* __restrict__ out)
{
    int o = blockIdx.x * 256 + threadIdx.x;
    if (o >= BB * LD) return;
    int b  = o / LD;
    int ld = o - b * LD;
    int l  = ld / DD;
    int d  = ld - l * DD;
    float s = bias[ld];
    const float* wp = weight + (size_t)l * FF * DD + d;
    const float* fp = f + (size_t)b * FF;
    for (int fi = 0; fi < FF; ++fi)
        s = fmaf(fp[fi], wp[(size_t)fi * DD], s);
    out[o] = s;
}

extern "C" void kernel_launch(void* const* d_in, const int* in_sizes, int n_in,
                              void* d_out, int out_size, void* d_ws, size_t ws_size,
                              hipStream_t stream)
{
    const float* f      = (const float*)d_in[0];   // 32 x 65536
    const float* weight = (const float*)d_in[1];   // 2 x 65536 x 768
    const float* bias   = (const float*)d_in[2];   // 2 x 768
    float* out          = (float*)d_out;           // 32 x 2 x 768

    if (ws_size < FT_BYTES + CHUNK_BYTES) {
        cc_direct<<<(BB * LD + 255) / 256, 256, 0, stream>>>(f, weight, bias, out);
        return;
    }

    int nf = (int)((ws_size - FT_BYTES) / CHUNK_BYTES);
    if (nf > 256) nf = 256;
    int chunk4 = (F4 + nf - 1) / nf;        // 64 when nf=256
    nf = (F4 + chunk4 - 1) / chunk4;

    float4* fT4      = (float4*)d_ws;
    float*  partials = (float*)((char*)d_ws + FT_BYTES);

    cc_transpose<<<(int)((FT_FLOAT4S + 255) / 256), 256, 0, stream>>>(
        (const float4*)f, fT4);

    dim3 grid1(3, nf);
    cc_stage1<<<grid1, 256, 0, stream>>>(fT4, weight, partials, chunk4);

    cc_stage2<<<(BB * LD + 255) / 256, 256, 0, stream>>>(
        partials, bias, out, nf);
}

// Round 9
// 192.088 us; speedup vs baseline: 1.4685x; 1.4685x over previous
//
#include <hip/hip_runtime.h>

// Problem constants: B=32, L=2, F=65536, D=768
#define BB 32
#define LL 2
#define FF 65536
#define DD 768
#define F4 (FF / 4)        // 16384 groups of 4 f
#define LD (LL * DD)       // 1536
#define LD2 (LD / 2)       // 768 float2
#define D2 (DD / 2)        // 384 float2 per weight row

#define FT_FLOAT4S ((size_t)F4 * BB)            // 524288 float4 = 8.39 MB
#define FT_BYTES   (FT_FLOAT4S * sizeof(float4))
#define CHUNK_BYTES ((size_t)BB * LD * sizeof(float))  // 196608 B
#define SUBC 64                                  // groups staged per LDS round

#define FMA2(A, W, S)                                                          \
    do {                                                                       \
        (A).x = fmaf((W).x, (S), (A).x);                                       \
        (A).y = fmaf((W).y, (S), (A).y);                                       \
    } while (0)

// Stage 0: transpose f (B x F) -> fT[g][b] as float4.
__global__ __launch_bounds__(256) void cc_transpose(
    const float4* __restrict__ f4, float4* __restrict__ fT4)
{
    size_t t = (size_t)blockIdx.x * 256 + threadIdx.x;   // 0 .. F4*32-1
    if (t >= FT_FLOAT4S) return;
    int b = (int)(t / F4);
    int g = (int)(t - (size_t)b * F4);
    fT4[(size_t)g * BB + b] = f4[t];
}

// Stage 1: partial GEMM over an F-chunk. 4 waves/block, f staged in LDS.
// grid = (3, NF); block = 256.  wave w covers ct = bx*4 + w; l = ct/6, dt = ct%6.
// Each wave: d-tile of 128 (float2/lane), acc[32] float2 = 64 VGPR.
// __launch_bounds__(256, 2): VGPR cap 256 (vs R8's (256,4) -> 64-VGPR cap and
// catastrophic scratch spill, WRITE_SIZE 273 MB). 2 blocks/CU = 8 waves/CU.
// partials[c][b][l*768 + dt*128 + lane*2]
__global__ __launch_bounds__(256, 2) void cc_stage1(
    const float4* __restrict__ fT4,     // [F4][32] float4
    const float* __restrict__ weight,   // L x F x D
    float* __restrict__ partials,       // NF x B x LD
    int chunk4)
{
    __shared__ float4 sf[SUBC * BB];    // 32 KB: f values for 64 groups

    const int tid  = threadIdx.x;
    const int lane = tid & 63;
    const int w    = tid >> 6;          // wave 0..3
    const int ct   = blockIdx.x * 4 + w;   // 0..11
    const int c    = blockIdx.y;           // chunk
    const int l    = ct / 6;
    const int dt   = ct - l * 6;

    const float2* __restrict__ w2p =
        (const float2*)weight + (size_t)l * FF * D2 + (size_t)dt * 64 + lane;

    int g0 = c * chunk4;
    int g1 = g0 + chunk4;
    if (g1 > F4) g1 = F4;

    float2 acc[BB];
#pragma unroll
    for (int b = 0; b < BB; ++b) acc[b] = make_float2(0.f, 0.f);

    // depth-1 weight prefetch for group g0
    float2 w0 = w2p[((size_t)g0 * 4 + 0) * D2];
    float2 w1 = w2p[((size_t)g0 * 4 + 1) * D2];
    float2 w2 = w2p[((size_t)g0 * 4 + 2) * D2];
    float2 w3 = w2p[((size_t)g0 * 4 + 3) * D2];

    for (int gs = g0; gs < g1; gs += SUBC) {
        int gcnt = g1 - gs;
        if (gcnt > SUBC) gcnt = SUBC;

        __syncthreads();   // previous round's LDS reads complete
        // cooperative stage: gcnt*32 float4s, fully coalesced
        for (int t = tid; t < gcnt * BB; t += 256)
            sf[t] = fT4[(size_t)gs * BB + t];
        __syncthreads();

        for (int gi = 0; gi < gcnt; ++gi) {
            const int g  = gs + gi;
            int gn = g + 1;
            if (gn >= g1) gn = g1 - 1;   // clamp: last iter reloads, harmless
            float2 n0 = w2p[((size_t)gn * 4 + 0) * D2];
            float2 n1 = w2p[((size_t)gn * 4 + 1) * D2];
            float2 n2 = w2p[((size_t)gn * 4 + 2) * D2];
            float2 n3 = w2p[((size_t)gn * 4 + 3) * D2];

            const float4* __restrict__ fr = sf + gi * BB;  // wave-uniform -> broadcast
#pragma unroll
            for (int b = 0; b < BB; ++b) {
                float4 fv = fr[b];
                FMA2(acc[b], w0, fv.x);
                FMA2(acc[b], w1, fv.y);
                FMA2(acc[b], w2, fv.z);
                FMA2(acc[b], w3, fv.w);
            }
            w0 = n0; w1 = n1; w2 = n2; w3 = n3;
        }
    }

    float2* __restrict__ out2 =
        (float2*)partials + (size_t)c * BB * LD2 + (size_t)(l * 384 + dt * 64 + lane);
#pragma unroll
    for (int b = 0; b < BB; ++b)
        out2[(size_t)b * LD2] = acc[b];
}

// Stage 2: out[b, ld] = bias[ld] + sum_c partials[c][b][ld]
__global__ __launch_bounds__(256) void cc_stage2(
    const float* __restrict__ partials,
    const float* __restrict__ bias,
    float* __restrict__ out,
    int nf)
{
    int o = blockIdx.x * 256 + threadIdx.x;   // 0 .. B*LD-1
    if (o >= BB * LD) return;
    int b  = o / LD;
    int ld = o - b * LD;
    float s = bias[ld];
    const float* __restrict__ p = partials + (size_t)b * LD + ld;
#pragma unroll 16
    for (int c = 0; c < nf; ++c)
        s += p[(size_t)c * (BB * LD)];
    out[o] = s;
}

// Correctness-only fallback if workspace is too small.
__global__ __launch_bounds__(256) void cc_direct(
    const float* __restrict__ f,
    const float* __restrict__ weight,
    const float* __restrict__ bias,
    float* __restrict__ out)
{
    int o = blockIdx.x * 256 + threadIdx.x;
    if (o >= BB * LD) return;
    int b  = o / LD;
    int ld = o - b * LD;
    int l  = ld / DD;
    int d  = ld - l * DD;
    float s = bias[ld];
    const float* wp = weight + (size_t)l * FF * DD + d;
    const float* fp = f + (size_t)b * FF;
    for (int fi = 0; fi < FF; ++fi)
        s = fmaf(fp[fi], wp[(size_t)fi * DD], s);
    out[o] = s;
}

extern "C" void kernel_launch(void* const* d_in, const int* in_sizes, int n_in,
                              void* d_out, int out_size, void* d_ws, size_t ws_size,
                              hipStream_t stream)
{
    const float* f      = (const float*)d_in[0];   // 32 x 65536
    const float* weight = (const float*)d_in[1];   // 2 x 65536 x 768
    const float* bias   = (const float*)d_in[2];   // 2 x 768
    float* out          = (float*)d_out;           // 32 x 2 x 768

    if (ws_size < FT_BYTES + CHUNK_BYTES) {
        cc_direct<<<(BB * LD + 255) / 256, 256, 0, stream>>>(f, weight, bias, out);
        return;
    }

    int nf = (int)((ws_size - FT_BYTES) / CHUNK_BYTES);
    if (nf > 256) nf = 256;
    int chunk4 = (F4 + nf - 1) / nf;        // 64 when nf=256
    nf = (F4 + chunk4 - 1) / chunk4;

    float4* fT4      = (float4*)d_ws;
    float*  partials = (float*)((char*)d_ws + FT_BYTES);

    cc_transpose<<<(int)((FT_FLOAT4S + 255) / 256), 256, 0, stream>>>(
        (const float4*)f, fT4);

    dim3 grid1(3, nf);
    cc_stage1<<<grid1, 256, 0, stream>>>(fT4, weight, partials, chunk4);

    cc_stage2<<<(BB * LD + 255) / 256, 256, 0, stream>>>(
        partials, bias, out, nf);
}

// Round 11
// 172.236 us; speedup vs baseline: 1.6377x; 1.1153x over previous
//
#include <hip/hip_runtime.h>

// Problem constants: B=32, L=2, F=65536, D=768
#define BB 32
#define LL 2
#define FF 65536
#define DD 768
#define F4 (FF / 4)        // 16384 groups of 4 f
#define LD (LL * DD)       // 1536
#define LD4 (LD / 4)       // 384 float4
#define D4 (DD / 4)        // 192 float4 per weight row

#define FT_FLOAT4S ((size_t)F4 * BB)            // 524288 float4 = 8.39 MB
#define FT_BYTES   (FT_FLOAT4S * sizeof(float4))
#define CHUNK_BYTES ((size_t)BB * LD * sizeof(float))  // 196608 B

#define FMA4(A, W, S)                                                          \
    do {                                                                       \
        (A).x = fmaf((W).x, (S), (A).x);                                       \
        (A).y = fmaf((W).y, (S), (A).y);                                       \
        (A).z = fmaf((W).z, (S), (A).z);                                       \
        (A).w = fmaf((W).w, (S), (A).w);                                       \
    } while (0)

// Stage 0: transpose f (B x F) -> fT[g][b] as float4.
__global__ __launch_bounds__(256) void cc_transpose(
    const float4* __restrict__ f4, float4* __restrict__ fT4)
{
    size_t t = (size_t)blockIdx.x * 256 + threadIdx.x;   // 0 .. F4*32-1
    if (t >= FT_FLOAT4S) return;
    int b = (int)(t / F4);
    int g = (int)(t - (size_t)b * F4);
    fT4[(size_t)g * BB + b] = f4[t];
}

// Stage 1: partial GEMM over an F-chunk. float4 d-tile (256 d / wave),
// depth-1 weight prefetch + 4x8 ping-pong-pipelined f batches.
// grid = (6, NF); block = 64 (one wave).  ct: l = ct/3, dt = ct%3.
// partials[c][b][l*768 + dt*256 + lane*4]
// VGPR ~240: acc 128 + w 32 + f ping-pong 64 + addr. (64,2) -> cap 256, no
// spill (R6/R8 lesson: a cap below demand causes catastrophic scratch spill).
__global__ __launch_bounds__(64, 2) void cc_stage1(
    const float4* __restrict__ fT4,     // [F4][32] float4
    const float* __restrict__ weight,   // L x F x D
    float* __restrict__ partials,       // NF x B x LD
    int chunk4)
{
    const int lane = threadIdx.x;
    const int ct   = blockIdx.x;        // 0..5
    const int c    = blockIdx.y;        // chunk
    const int l    = ct / 3;
    const int dt   = ct - l * 3;

    const float4* __restrict__ w4p =
        (const float4*)weight + (size_t)l * FF * D4 + (size_t)dt * 64 + lane;

    int g0 = c * chunk4;
    int g1 = g0 + chunk4;
    if (g1 > F4) g1 = F4;

    float4 acc[BB];
#pragma unroll
    for (int b = 0; b < BB; ++b) acc[b] = make_float4(0.f, 0.f, 0.f, 0.f);

    // current-group weight rows
    float4 wa0 = w4p[((size_t)g0 * 4 + 0) * D4];
    float4 wa1 = w4p[((size_t)g0 * 4 + 1) * D4];
    float4 wa2 = w4p[((size_t)g0 * 4 + 2) * D4];
    float4 wa3 = w4p[((size_t)g0 * 4 + 3) * D4];

    // f ping-pong batches (8 float4 each)
    float4 pA[8], pB[8];
    {
        const float4* __restrict__ fg = fT4 + (size_t)g0 * BB;
#pragma unroll
        for (int i = 0; i < 8; ++i) pA[i] = fg[i];
    }

    for (int g = g0; g < g1; ++g) {
        int gn = (g + 1 < g1) ? (g + 1) : g;   // clamp: last iter reloads, harmless
        // next-group weight rows (in flight across this group's 1024-cy FMA)
        float4 wb0 = w4p[((size_t)gn * 4 + 0) * D4];
        float4 wb1 = w4p[((size_t)gn * 4 + 1) * D4];
        float4 wb2 = w4p[((size_t)gn * 4 + 2) * D4];
        float4 wb3 = w4p[((size_t)gn * 4 + 3) * D4];

        const float4* __restrict__ fg  = fT4 + (size_t)g  * BB;
        const float4* __restrict__ fgn = fT4 + (size_t)gn * BB;

        // pB <- b 8..15, then FMA batch 0 (b 0..7) from pA
#pragma unroll
        for (int i = 0; i < 8; ++i) pB[i] = fg[8 + i];
#pragma unroll
        for (int i = 0; i < 8; ++i) {
            float4 fv = pA[i];
            FMA4(acc[i], wa0, fv.x);
            FMA4(acc[i], wa1, fv.y);
            FMA4(acc[i], wa2, fv.z);
            FMA4(acc[i], wa3, fv.w);
        }
        // pA <- b 16..23, FMA batch 1 (b 8..15) from pB
#pragma unroll
        for (int i = 0; i < 8; ++i) pA[i] = fg[16 + i];
#pragma unroll
        for (int i = 0; i < 8; ++i) {
            float4 fv = pB[i];
            FMA4(acc[8 + i], wa0, fv.x);
            FMA4(acc[8 + i], wa1, fv.y);
            FMA4(acc[8 + i], wa2, fv.z);
            FMA4(acc[8 + i], wa3, fv.w);
        }
        // pB <- b 24..31, FMA batch 2 (b 16..23) from pA
#pragma unroll
        for (int i = 0; i < 8; ++i) pB[i] = fg[24 + i];
#pragma unroll
        for (int i = 0; i < 8; ++i) {
            float4 fv = pA[i];
            FMA4(acc[16 + i], wa0, fv.x);
            FMA4(acc[16 + i], wa1, fv.y);
            FMA4(acc[16 + i], wa2, fv.z);
            FMA4(acc[16 + i], wa3, fv.w);
        }
        // pA <- NEXT group's b 0..7, FMA batch 3 (b 24..31) from pB
#pragma unroll
        for (int i = 0; i < 8; ++i) pA[i] = fgn[i];
#pragma unroll
        for (int i = 0; i < 8; ++i) {
            float4 fv = pB[i];
            FMA4(acc[24 + i], wa0, fv.x);
            FMA4(acc[24 + i], wa1, fv.y);
            FMA4(acc[24 + i], wa2, fv.z);
            FMA4(acc[24 + i], wa3, fv.w);
        }
        // rotate weight buffers
        wa0 = wb0; wa1 = wb1; wa2 = wb2; wa3 = wb3;
    }

    float4* __restrict__ out4 =
        (float4*)partials + (size_t)c * BB * LD4 + (size_t)(l * 192 + dt * 64 + lane);
#pragma unroll
    for (int b = 0; b < BB; ++b)
        out4[(size_t)b * LD4] = acc[b];
}

// Stage 2: out[b, ld] = bias[ld] + sum_c partials[c][b][ld]
__global__ __launch_bounds__(256) void cc_stage2(
    const float* __restrict__ partials,
    const float* __restrict__ bias,
    float* __restrict__ out,
    int nf)
{
    int o = blockIdx.x * 256 + threadIdx.x;   // 0 .. B*LD-1
    if (o >= BB * LD) return;
    int b  = o / LD;
    int ld = o - b * LD;
    float s = bias[ld];
    const float* __restrict__ p = partials + (size_t)b * LD + ld;
#pragma unroll 16
    for (int c = 0; c < nf; ++c)
        s += p[(size_t)c * (BB * LD)];
    out[o] = s;
}

// Correctness-only fallback if workspace is too small.
__global__ __launch_bounds__(256) void cc_direct(
    const float* __restrict__ f,
    const float* __restrict__ weight,
    const float* __restrict__ bias,
    float* __restrict__ out)
{
    int o = blockIdx.x * 256 + threadIdx.x;
    if (o >= BB * LD) return;
    int b  = o / LD;
    int ld = o - b * LD;
    int l  = ld / DD;
    int d  = ld - l * DD;
    float s = bias[ld];
    const float* wp = weight + (size_t)l * FF * DD + d;
    const float* fp = f + (size_t)b * FF;
    for (int fi = 0; fi < FF; ++fi)
        s = fmaf(fp[fi], wp[(size_t)fi * DD], s);
    out[o] = s;
}

extern "C" void kernel_launch(void* const* d_in, const int* in_sizes, int n_in,
                              void* d_out, int out_size, void* d_ws, size_t ws_size,
                              hipStream_t stream)
{
    const float* f      = (const float*)d_in[0];   // 32 x 65536
    const float* weight = (const float*)d_in[1];   // 2 x 65536 x 768
    const float* bias   = (const float*)d_in[2];   // 2 x 768
    float* out          = (float*)d_out;           // 32 x 2 x 768

    if (ws_size < FT_BYTES + CHUNK_BYTES) {
        cc_direct<<<(BB * LD + 255) / 256, 256, 0, stream>>>(f, weight, bias, out);
        return;
    }

    int nf = (int)((ws_size - FT_BYTES) / CHUNK_BYTES);
    if (nf > 256) nf = 256;
    int chunk4 = (F4 + nf - 1) / nf;        // 64 when nf=256
    nf = (F4 + chunk4 - 1) / chunk4;

    float4* fT4      = (float4*)d_ws;
    float*  partials = (float*)((char*)d_ws + FT_BYTES);

    cc_transpose<<<(int)((FT_FLOAT4S + 255) / 256), 256, 0, stream>>>(
        (const float4*)f, fT4);

    dim3 grid1(6, nf);
    cc_stage1<<<grid1, 64, 0, stream>>>(fT4, weight, partials, chunk4);

    cc_stage2<<<(BB * LD + 255) / 256, 256, 0, stream>>>(
        partials, bias, out, nf);
}

// Round 12
// 151.041 us; speedup vs baseline: 1.8675x; 1.1403x over previous
//
#include <hip/hip_runtime.h>

// Problem constants: B=32, L=2, F=65536, D=768
#define BB 32
#define LL 2
#define FF 65536
#define DD 768
#define F4 (FF / 4)        // 16384 groups of 4 f
#define LD (LL * DD)       // 1536
#define LD4 (LD / 4)       // 384 float4
#define D4 (DD / 4)        // 192 float4 per weight row

#define FT_FLOAT4S ((size_t)F4 * BB)            // 524288 float4 = 8.39 MB
#define FT_BYTES   (FT_FLOAT4S * sizeof(float4))
#define CHUNK_BYTES ((size_t)BB * LD * sizeof(float))  // 196608 B
#define NFMAX 512

#define FMA4(A, W, S)                                                          \
    do {                                                                       \
        (A).x = fmaf((W).x, (S), (A).x);                                       \
        (A).y = fmaf((W).y, (S), (A).y);                                       \
        (A).z = fmaf((W).z, (S), (A).z);                                       \
        (A).w = fmaf((W).w, (S), (A).w);                                       \
    } while (0)

// Stage 0: transpose f (B x F) -> fT[g][b] as float4.
__global__ __launch_bounds__(256) void cc_transpose(
    const float4* __restrict__ f4, float4* __restrict__ fT4)
{
    size_t t = (size_t)blockIdx.x * 256 + threadIdx.x;   // 0 .. F4*32-1
    if (t >= FT_FLOAT4S) return;
    int b = (int)(t / F4);
    int g = (int)(t - (size_t)b * F4);
    fT4[(size_t)g * BB + b] = f4[t];
}

// Stage 1: partial GEMM over an F-chunk. float4 d-tile (256 d / wave),
// depth-1 weight prefetch + 4x8 ping-pong-pipelined f batches.
// grid = (6, NF=512); block = 64 (one wave).  ct: l = ct/3, dt = ct%3.
// 3072 waves -> ~2 resident/SIMD (VGPR ~240, (64,2) cap 256, no spill).
// partials[c][b][l*768 + dt*256 + lane*4]
__global__ __launch_bounds__(64, 2) void cc_stage1(
    const float4* __restrict__ fT4,     // [F4][32] float4
    const float* __restrict__ weight,   // L x F x D
    float* __restrict__ partials,       // NF x B x LD
    int chunk4)
{
    const int lane = threadIdx.x;
    const int ct   = blockIdx.x;        // 0..5
    const int c    = blockIdx.y;        // chunk
    const int l    = ct / 3;
    const int dt   = ct - l * 3;

    const float4* __restrict__ w4p =
        (const float4*)weight + (size_t)l * FF * D4 + (size_t)dt * 64 + lane;

    int g0 = c * chunk4;
    int g1 = g0 + chunk4;
    if (g1 > F4) g1 = F4;

    float4 acc[BB];
#pragma unroll
    for (int b = 0; b < BB; ++b) acc[b] = make_float4(0.f, 0.f, 0.f, 0.f);

    // current-group weight rows
    float4 wa0 = w4p[((size_t)g0 * 4 + 0) * D4];
    float4 wa1 = w4p[((size_t)g0 * 4 + 1) * D4];
    float4 wa2 = w4p[((size_t)g0 * 4 + 2) * D4];
    float4 wa3 = w4p[((size_t)g0 * 4 + 3) * D4];

    // f ping-pong batches (8 float4 each)
    float4 pA[8], pB[8];
    {
        const float4* __restrict__ fg = fT4 + (size_t)g0 * BB;
#pragma unroll
        for (int i = 0; i < 8; ++i) pA[i] = fg[i];
    }

    for (int g = g0; g < g1; ++g) {
        int gn = (g + 1 < g1) ? (g + 1) : g;   // clamp: last iter reloads, harmless
        // next-group weight rows (in flight across this group's 1024-cy FMA)
        float4 wb0 = w4p[((size_t)gn * 4 + 0) * D4];
        float4 wb1 = w4p[((size_t)gn * 4 + 1) * D4];
        float4 wb2 = w4p[((size_t)gn * 4 + 2) * D4];
        float4 wb3 = w4p[((size_t)gn * 4 + 3) * D4];

        const float4* __restrict__ fg  = fT4 + (size_t)g  * BB;
        const float4* __restrict__ fgn = fT4 + (size_t)gn * BB;

        // pB <- b 8..15, then FMA batch 0 (b 0..7) from pA
#pragma unroll
        for (int i = 0; i < 8; ++i) pB[i] = fg[8 + i];
#pragma unroll
        for (int i = 0; i < 8; ++i) {
            float4 fv = pA[i];
            FMA4(acc[i], wa0, fv.x);
            FMA4(acc[i], wa1, fv.y);
            FMA4(acc[i], wa2, fv.z);
            FMA4(acc[i], wa3, fv.w);
        }
        // pA <- b 16..23, FMA batch 1 (b 8..15) from pB
#pragma unroll
        for (int i = 0; i < 8; ++i) pA[i] = fg[16 + i];
#pragma unroll
        for (int i = 0; i < 8; ++i) {
            float4 fv = pB[i];
            FMA4(acc[8 + i], wa0, fv.x);
            FMA4(acc[8 + i], wa1, fv.y);
            FMA4(acc[8 + i], wa2, fv.z);
            FMA4(acc[8 + i], wa3, fv.w);
        }
        // pB <- b 24..31, FMA batch 2 (b 16..23) from pA
#pragma unroll
        for (int i = 0; i < 8; ++i) pB[i] = fg[24 + i];
#pragma unroll
        for (int i = 0; i < 8; ++i) {
            float4 fv = pA[i];
            FMA4(acc[16 + i], wa0, fv.x);
            FMA4(acc[16 + i], wa1, fv.y);
            FMA4(acc[16 + i], wa2, fv.z);
            FMA4(acc[16 + i], wa3, fv.w);
        }
        // pA <- NEXT group's b 0..7, FMA batch 3 (b 24..31) from pB
#pragma unroll
        for (int i = 0; i < 8; ++i) pA[i] = fgn[i];
#pragma unroll
        for (int i = 0; i < 8; ++i) {
            float4 fv = pB[i];
            FMA4(acc[24 + i], wa0, fv.x);
            FMA4(acc[24 + i], wa1, fv.y);
            FMA4(acc[24 + i], wa2, fv.z);
            FMA4(acc[24 + i], wa3, fv.w);
        }
        // rotate weight buffers
        wa0 = wb0; wa1 = wb1; wa2 = wb2; wa3 = wb3;
    }

    float4* __restrict__ out4 =
        (float4*)partials + (size_t)c * BB * LD4 + (size_t)(l * 192 + dt * 64 + lane);
#pragma unroll
    for (int b = 0; b < BB; ++b)
        out4[(size_t)b * LD4] = acc[b];
}

// Stage 2: out[b, ld] = bias[ld] + sum_c partials[c][b][ld]
__global__ __launch_bounds__(256) void cc_stage2(
    const float* __restrict__ partials,
    const float* __restrict__ bias,
    float* __restrict__ out,
    int nf)
{
    int o = blockIdx.x * 256 + threadIdx.x;   // 0 .. B*LD-1
    if (o >= BB * LD) return;
    int b  = o / LD;
    int ld = o - b * LD;
    float s = bias[ld];
    const float* __restrict__ p = partials + (size_t)b * LD + ld;
#pragma unroll 16
    for (int c = 0; c < nf; ++c)
        s += p[(size_t)c * (BB * LD)];
    out[o] = s;
}

// Correctness-only fallback if workspace is too small.
__global__ __launch_bounds__(256) void cc_direct(
    const float* __restrict__ f,
    const float* __restrict__ weight,
    const float* __restrict__ bias,
    float* __restrict__ out)
{
    int o = blockIdx.x * 256 + threadIdx.x;
    if (o >= BB * LD) return;
    int b  = o / LD;
    int ld = o - b * LD;
    int l  = ld / DD;
    int d  = ld - l * DD;
    float s = bias[ld];
    const float* wp = weight + (size_t)l * FF * DD + d;
    const float* fp = f + (size_t)b * FF;
    for (int fi = 0; fi < FF; ++fi)
        s = fmaf(fp[fi], wp[(size_t)fi * DD], s);
    out[o] = s;
}

extern "C" void kernel_launch(void* const* d_in, const int* in_sizes, int n_in,
                              void* d_out, int out_size, void* d_ws, size_t ws_size,
                              hipStream_t stream)
{
    const float* f      = (const float*)d_in[0];   // 32 x 65536
    const float* weight = (const float*)d_in[1];   // 2 x 65536 x 768
    const float* bias   = (const float*)d_in[2];   // 2 x 768
    float* out          = (float*)d_out;           // 32 x 2 x 768

    if (ws_size < FT_BYTES + CHUNK_BYTES) {
        cc_direct<<<(BB * LD + 255) / 256, 256, 0, stream>>>(f, weight, bias, out);
        return;
    }

    int nf = (int)((ws_size - FT_BYTES) / CHUNK_BYTES);
    if (nf > NFMAX) nf = NFMAX;
    int chunk4 = (F4 + nf - 1) / nf;        // 32 when nf=512
    nf = (F4 + chunk4 - 1) / chunk4;

    float4* fT4      = (float4*)d_ws;
    float*  partials = (float*)((char*)d_ws + FT_BYTES);

    cc_transpose<<<(int)((FT_FLOAT4S + 255) / 256), 256, 0, stream>>>(
        (const float4*)f, fT4);

    dim3 grid1(6, nf);
    cc_stage1<<<grid1, 64, 0, stream>>>(fT4, weight, partials, chunk4);

    cc_stage2<<<(BB * LD + 255) / 256, 256, 0, stream>>>(
        partials, bias, out, nf);
}